// Round 4
// baseline (567.704 us; speedup 1.0000x reference)
//
#include <hip/hip_runtime.h>

// Problem: B=16, L=4096, D=1024
//   out[b,l,d] = S[b,l,d] + sum_mod outmod[b,d]
//   outmod = ((feat @ Wkv^T + bkv) @ Wv^T + bv) @ Wo^T + bo
// dins: image=2048, audio=1024, text=768
//
// Key structural fact: the GEMV chain is tiny math (0.33 GFLOP) but the
// previous mapping (one wave per (m,b,d)) streamed every weight matrix B=16
// times (~1.3 GB of traffic). This version is BATCH-STATIONARY: one wave per
// (m,d) reads the weight row ONCE and accumulates all 16 batch dots in
// registers. Unique weight traffic = 40 MB total (~7 us at HBM BW); the
// activation rows are <=128 KB per modality and stay L1/L2 resident.

#define B_ 16
#define L_ 4096
#define D_ 1024

typedef float v4f __attribute__((ext_vector_type(4)));

struct AllBArgs {
    const float* x[3];    // [B, K[m]]  activations
    const float* W[3];    // [D, K[m]]  weights (row-major, row = output dim)
    const float* bias[3]; // [D]
    float*       y[3];    // [B, D]
    int          K[3];
};

// One wave per (m, d): 3*1024 waves. Each wave reads W[m][d,:] once and
// computes y[m][b,d] for ALL b in 0..15 (16 register accumulators).
// Grid: 768 blocks * 256 threads = 3072 waves.
__global__ __launch_bounds__(256) void gemv_allb(AllBArgs a) {
    int wid  = (blockIdx.x * 256 + threadIdx.x) >> 6;
    int lane = threadIdx.x & 63;
    int m = wid >> 10;
    int d = wid & 1023;
    int K = a.K[m];

    const float* wr = a.W[m] + (size_t)d * K;
    const float* xb = a.x[m];

    float sum[16];
    #pragma unroll
    for (int b = 0; b < 16; ++b) sum[b] = 0.f;

    for (int k = lane * 4; k < K; k += 256) {
        float4 wv = *(const float4*)(wr + k);
        #pragma unroll
        for (int b = 0; b < 16; ++b) {
            float4 xv = *(const float4*)(xb + b * K + k);
            sum[b] += xv.x * wv.x + xv.y * wv.y + xv.z * wv.z + xv.w * wv.w;
        }
    }

    float bias = a.bias[m][d];
    #pragma unroll
    for (int b = 0; b < 16; ++b) {
        float s = sum[b];
        for (int off = 32; off; off >>= 1) s += __shfl_xor(s, off, 64);
        if (lane == 0) a.y[m][(b << 10) + d] = s + bias;
    }
}

struct Stage3Args {
    const float* v0; const float* v1; const float* v2;   // [B, D] each
    const float* W0; const float* W1; const float* W2;   // [D, D] each
    const float* b0; const float* b1; const float* b2;   // [D]
    float* delta;                                        // [B, D]
};

// One wave per d (1024 waves, 256 blocks): delta[b,d] for all b, summing the
// three modalities. Each Wo row is read once.
__global__ __launch_bounds__(256) void gemv3_allb(Stage3Args a) {
    int wid  = (blockIdx.x * 256 + threadIdx.x) >> 6;
    int lane = threadIdx.x & 63;
    int d = wid & 1023;

    const float* xs[3] = { a.v0, a.v1, a.v2 };
    const float* ws[3] = { a.W0 + ((size_t)d << 10), a.W1 + ((size_t)d << 10),
                           a.W2 + ((size_t)d << 10) };

    float sum[16];
    #pragma unroll
    for (int b = 0; b < 16; ++b) sum[b] = 0.f;

    #pragma unroll
    for (int m = 0; m < 3; ++m) {
        const float* wr = ws[m];
        const float* xb = xs[m];
        #pragma unroll
        for (int k = lane * 4; k < 1024; k += 256) {
            float4 wv = *(const float4*)(wr + k);
            #pragma unroll
            for (int b = 0; b < 16; ++b) {
                float4 xv = *(const float4*)(xb + (b << 10) + k);
                sum[b] += xv.x * wv.x + xv.y * wv.y + xv.z * wv.z + xv.w * wv.w;
            }
        }
    }

    float bias = a.b0[d] + a.b1[d] + a.b2[d];
    #pragma unroll
    for (int b = 0; b < 16; ++b) {
        float s = sum[b];
        for (int off = 32; off; off >>= 1) s += __shfl_xor(s, off, 64);
        if (lane == 0) a.delta[(b << 10) + d] = s + bias;
    }
}

// out[b,l,d] = S[b,l,d] + delta[b,d]
// Column-stationary: each thread owns one (b, d4) float4 column, walks 32
// consecutive l rows; delta register-resident; pure nontemporal stream.
__global__ __launch_bounds__(256) void add_bcast(const v4f* __restrict__ S,
                                                 const v4f* __restrict__ delta,
                                                 v4f* __restrict__ out) {
    int tid   = blockIdx.x * 256 + threadIdx.x;
    int d4    = tid & 255;          // float4 column within D
    int chunk = (tid >> 8) & 127;   // which 32-row chunk of L
    int b     = tid >> 15;          // batch

    v4f dl = delta[(b << 8) + d4];

    size_t base = ((size_t)b << 20) + ((size_t)chunk << 13) + (size_t)d4;

    #pragma unroll 8
    for (int j = 0; j < 32; ++j) {
        size_t idx = base + ((size_t)j << 8);
        v4f s = __builtin_nontemporal_load(S + idx);
        __builtin_nontemporal_store(s + dl, out + idx);
    }
}

extern "C" void kernel_launch(void* const* d_in, const int* in_sizes, int n_in,
                              void* d_out, int out_size, void* d_ws, size_t ws_size,
                              hipStream_t stream) {
    const float* S = (const float*)d_in[0];

    const int dins[3] = {2048, 1024, 768};
    const float *feat[3], *Wkv[3], *bkv[3], *Wv[3], *bv[3], *Wo[3], *bo[3];
    for (int m = 0; m < 3; ++m) {
        int base = 1 + m * 7;
        feat[m] = (const float*)d_in[base + 0];
        Wkv[m]  = (const float*)d_in[base + 1];
        bkv[m]  = (const float*)d_in[base + 2];
        Wv[m]   = (const float*)d_in[base + 3];
        bv[m]   = (const float*)d_in[base + 4];
        Wo[m]   = (const float*)d_in[base + 5];
        bo[m]   = (const float*)d_in[base + 6];
    }

    float* ws = (float*)d_ws;
    const int BD = B_ * D_;
    float* kv[3]  = {ws, ws + BD, ws + 2 * BD};
    float* v[3]   = {ws + 3 * BD, ws + 4 * BD, ws + 5 * BD};
    float* delta  = ws + 6 * BD;

    // Stage 1: kv[m] = feat[m] @ Wkv[m]^T + bkv[m]   (batch-stationary)
    AllBArgs s1;
    for (int m = 0; m < 3; ++m) {
        s1.x[m] = feat[m]; s1.W[m] = Wkv[m]; s1.bias[m] = bkv[m];
        s1.y[m] = kv[m];   s1.K[m] = dins[m];
    }
    gemv_allb<<<768, 256, 0, stream>>>(s1);

    // Stage 2: v[m] = kv[m] @ Wv[m]^T + bv[m]
    AllBArgs s2;
    for (int m = 0; m < 3; ++m) {
        s2.x[m] = kv[m]; s2.W[m] = Wv[m]; s2.bias[m] = bv[m];
        s2.y[m] = v[m];  s2.K[m] = D_;
    }
    gemv_allb<<<768, 256, 0, stream>>>(s2);

    // Stage 3: delta = sum_m (v[m] @ Wo[m]^T + bo[m])
    Stage3Args s3 = { v[0], v[1], v[2], Wo[0], Wo[1], Wo[2], bo[0], bo[1], bo[2], delta };
    gemv3_allb<<<256, 256, 0, stream>>>(s3);

    // Broadcast add: column-stationary streaming kernel
    add_bcast<<<2048, 256, 0, stream>>>((const v4f*)S, (const v4f*)delta,
                                        (v4f*)d_out);
}

// Round 6
// 537.699 us; speedup vs baseline: 1.0558x; 1.0558x over previous
//
#include <hip/hip_runtime.h>

// Problem: B=16, L=4096, D=1024
//   out[b,l,d] = S[b,l,d] + sum_mod outmod[b,d]
//   outmod = ((feat @ Wkv^T + bkv) @ Wv^T + bv) @ Wo^T + bo
// dins: image=2048, audio=1024, text=768
//
// Evidence so far (rounds 1+4): all weights (~40 MB) are L3-resident, so the
// GEMV chain is latency-, not traffic-bound. Total dur_us (~541-568) is
// dominated by harness re-poison fills (1.07 GB @ 6.5 TB/s = 163 us each, one
// per iteration) -- our four dispatches are each <163 us. This version
// minimizes the controllable share: compile-time-K GEMV bodies (static trip
// counts -> deep load pipelining) and a wider fully-unrolled streaming add.

#define B_ 16
#define L_ 4096
#define D_ 1024

typedef float v4f __attribute__((ext_vector_type(4)));

struct AllBArgs {
    const float* x[3];    // [B, K[m]]  activations
    const float* W[3];    // [D, K[m]]  weights (row-major, row = output dim)
    const float* bias[3]; // [D]
    float*       y[3];    // [B, D]
};

// Batch-stationary GEMV body: one wave handles output dim d for ALL 16 b.
// K compile-time -> static trip count, full address precompute, deep MLP.
template<int K>
__device__ __forceinline__ void gemv_body(const float* __restrict__ x,
                                          const float* __restrict__ W,
                                          const float* __restrict__ bias,
                                          float* __restrict__ y,
                                          int d, int lane) {
    const float* wr = W + (size_t)d * K;

    float sum[16];
    #pragma unroll
    for (int b = 0; b < 16; ++b) sum[b] = 0.f;

    #pragma unroll 2
    for (int k0 = 0; k0 < K; k0 += 256) {
        int k = k0 + lane * 4;
        float4 wv = *(const float4*)(wr + k);
        #pragma unroll
        for (int b = 0; b < 16; ++b) {
            float4 xv = *(const float4*)(x + b * K + k);
            sum[b] += xv.x * wv.x + xv.y * wv.y + xv.z * wv.z + xv.w * wv.w;
        }
    }

    float bb = bias[d];
    #pragma unroll
    for (int b = 0; b < 16; ++b) {
        float s = sum[b];
        for (int off = 32; off; off >>= 1) s += __shfl_xor(s, off, 64);
        if (lane == 0) y[(b << 10) + d] = s + bb;
    }
}

// 3*1024 waves: wave -> (m, d). Blocks 0..255 m=0, 256..511 m=1, 512..767 m=2
// (branch is block-uniform). Grid: 768 blocks * 256 threads.
__global__ __launch_bounds__(256) void gemv_allb(AllBArgs a) {
    int wid  = (blockIdx.x * 256 + threadIdx.x) >> 6;
    int lane = threadIdx.x & 63;
    int m = wid >> 10;
    int d = wid & 1023;

    if (m == 0)      gemv_body<2048>(a.x[0], a.W[0], a.bias[0], a.y[0], d, lane);
    else if (m == 1) gemv_body<1024>(a.x[1], a.W[1], a.bias[1], a.y[1], d, lane);
    else             gemv_body< 768>(a.x[2], a.W[2], a.bias[2], a.y[2], d, lane);
}

// Stage 2 is three K=1024 GEMVs with the same mapping.
__global__ __launch_bounds__(256) void gemv_allb2(AllBArgs a) {
    int wid  = (blockIdx.x * 256 + threadIdx.x) >> 6;
    int lane = threadIdx.x & 63;
    int m = wid >> 10;
    int d = wid & 1023;
    gemv_body<1024>(a.x[m], a.W[m], a.bias[m], a.y[m], d, lane);
}

struct Stage3Args {
    const float* v0; const float* v1; const float* v2;   // [B, D] each
    const float* W0; const float* W1; const float* W2;   // [D, D] each
    const float* b0; const float* b1; const float* b2;   // [D]
    float* delta;                                        // [B, D]
};

// One wave per d (1024 waves, 256 blocks): delta[b,d] for all b, summing the
// three modalities. Static K=1024 loops.
__global__ __launch_bounds__(256) void gemv3_allb(Stage3Args a) {
    int wid  = (blockIdx.x * 256 + threadIdx.x) >> 6;
    int lane = threadIdx.x & 63;
    int d = wid & 1023;

    const float* xs[3] = { a.v0, a.v1, a.v2 };
    const float* ws[3] = { a.W0 + ((size_t)d << 10), a.W1 + ((size_t)d << 10),
                           a.W2 + ((size_t)d << 10) };

    float sum[16];
    #pragma unroll
    for (int b = 0; b < 16; ++b) sum[b] = 0.f;

    #pragma unroll
    for (int m = 0; m < 3; ++m) {
        const float* wr = ws[m];
        const float* xb = xs[m];
        #pragma unroll 2
        for (int k0 = 0; k0 < 1024; k0 += 256) {
            int k = k0 + lane * 4;
            float4 wv = *(const float4*)(wr + k);
            #pragma unroll
            for (int b = 0; b < 16; ++b) {
                float4 xv = *(const float4*)(xb + (b << 10) + k);
                sum[b] += xv.x * wv.x + xv.y * wv.y + xv.z * wv.z + xv.w * wv.w;
            }
        }
    }

    float bias = a.b0[d] + a.b1[d] + a.b2[d];
    #pragma unroll
    for (int b = 0; b < 16; ++b) {
        float s = sum[b];
        for (int off = 32; off; off >>= 1) s += __shfl_xor(s, off, 64);
        if (lane == 0) a.delta[(b << 10) + d] = s + bias;
    }
}

// out[b,l,d] = S[b,l,d] + delta[b,d]
// Column-stationary: each thread owns one (b, d4) float4 column, walks 16
// consecutive l rows (fully unrolled); delta register-resident; nontemporal.
// Grid: 4096 blocks * 256 threads = 2^20 threads = 16 b * 256 chunks * 256 d4.
__global__ __launch_bounds__(256) void add_bcast(const v4f* __restrict__ S,
                                                 const v4f* __restrict__ delta,
                                                 v4f* __restrict__ out) {
    int tid   = blockIdx.x * 256 + threadIdx.x;
    int d4    = tid & 255;          // float4 column within D
    int chunk = (tid >> 8) & 255;   // which 16-row chunk of L
    int b     = tid >> 16;          // batch

    v4f dl = delta[(b << 8) + d4];

    // flat float4 index: (b<<20) + (l<<8) + d4 ; chunk covers 16 rows (<<12)
    size_t base = ((size_t)b << 20) + ((size_t)chunk << 12) + (size_t)d4;

    #pragma unroll
    for (int j = 0; j < 16; ++j) {
        size_t idx = base + ((size_t)j << 8);
        v4f s = __builtin_nontemporal_load(S + idx);
        __builtin_nontemporal_store(s + dl, out + idx);
    }
}

extern "C" void kernel_launch(void* const* d_in, const int* in_sizes, int n_in,
                              void* d_out, int out_size, void* d_ws, size_t ws_size,
                              hipStream_t stream) {
    const float* S = (const float*)d_in[0];

    const float *feat[3], *Wkv[3], *bkv[3], *Wv[3], *bv[3], *Wo[3], *bo[3];
    for (int m = 0; m < 3; ++m) {
        int base = 1 + m * 7;
        feat[m] = (const float*)d_in[base + 0];
        Wkv[m]  = (const float*)d_in[base + 1];
        bkv[m]  = (const float*)d_in[base + 2];
        Wv[m]   = (const float*)d_in[base + 3];
        bv[m]   = (const float*)d_in[base + 4];
        Wo[m]   = (const float*)d_in[base + 5];
        bo[m]   = (const float*)d_in[base + 6];
    }

    float* ws = (float*)d_ws;
    const int BD = B_ * D_;
    float* kv[3]  = {ws, ws + BD, ws + 2 * BD};
    float* v[3]   = {ws + 3 * BD, ws + 4 * BD, ws + 5 * BD};
    float* delta  = ws + 6 * BD;

    // Stage 1: kv[m] = feat[m] @ Wkv[m]^T + bkv[m]
    AllBArgs s1;
    for (int m = 0; m < 3; ++m) {
        s1.x[m] = feat[m]; s1.W[m] = Wkv[m]; s1.bias[m] = bkv[m]; s1.y[m] = kv[m];
    }
    gemv_allb<<<768, 256, 0, stream>>>(s1);

    // Stage 2: v[m] = kv[m] @ Wv[m]^T + bv[m]
    AllBArgs s2;
    for (int m = 0; m < 3; ++m) {
        s2.x[m] = kv[m]; s2.W[m] = Wv[m]; s2.bias[m] = bv[m]; s2.y[m] = v[m];
    }
    gemv_allb2<<<768, 256, 0, stream>>>(s2);

    // Stage 3: delta = sum_m (v[m] @ Wo[m]^T + bo[m])
    Stage3Args s3 = { v[0], v[1], v[2], Wo[0], Wo[1], Wo[2], bo[0], bo[1], bo[2], delta };
    gemv3_allb<<<256, 256, 0, stream>>>(s3);

    // Broadcast add: column-stationary streaming kernel
    add_bcast<<<4096, 256, 0, stream>>>((const v4f*)S, (const v4f*)delta,
                                        (v4f*)d_out);
}